// Round 8
// baseline (308.179 us; speedup 1.0000x reference)
//
#include <hip/hip_runtime.h>

#define HID 64
#define FEAT 10
#define STAGE_CAP 6144   // csr_build LDS staging entries (max bucket ~4400)

// ---------- helpers ----------
__device__ inline unsigned short f2bf(float f) {          // fp32 -> bf16 RNE
    unsigned u = __float_as_uint(f);
    unsigned r = (u + 0x7fffu + ((u >> 16) & 1u)) >> 16;
    return (unsigned short)r;
}
// decode 8 bf16 (uint4) and fma into acc[8] with weight w
__device__ inline void bf8_fma(float* acc, uint4 u, float w) {
    acc[0] += __uint_as_float(u.x << 16) * w;
    acc[1] += __uint_as_float(u.x & 0xffff0000u) * w;
    acc[2] += __uint_as_float(u.y << 16) * w;
    acc[3] += __uint_as_float(u.y & 0xffff0000u) * w;
    acc[4] += __uint_as_float(u.z << 16) * w;
    acc[5] += __uint_as_float(u.z & 0xffff0000u) * w;
    acc[6] += __uint_as_float(u.w << 16) * w;
    acc[7] += __uint_as_float(u.w & 0xffff0000u) * w;
}
// csr entry: u32 = (src << 16) | bf16_bits(weight)
__device__ inline int csr_src(unsigned e) { return (int)(e >> 16); }
__device__ inline float csr_w(unsigned e) { return __uint_as_float(e << 16); }

// ================= CSR build (bucketed, coalesced) =================

__global__ void histA(const int* __restrict__ dst, int* __restrict__ cnt,
                      int* __restrict__ cnt2T, int E, int nbuckets, int nchunks) {
    __shared__ int lh[256];
    int t = threadIdx.x, c = blockIdx.x;
    if (t < 256) lh[t] = 0;
    __syncthreads();
    int base = c * 4096;
    #pragma unroll
    for (int j = 0; j < 4; j++) {
        int e = base + t + j * 1024;
        if (e < E) {
            int d = dst[e];
            atomicAdd(&cnt[d], 1);
            atomicAdd(&lh[d >> 8], 1);
        }
    }
    __syncthreads();
    if (t < nbuckets) cnt2T[t * nchunks + c] = lh[t];
}

__global__ void bsum_kernel(const int* __restrict__ cnt, int* __restrict__ bsum, int N) {
    __shared__ int lds[256];
    int i = blockIdx.x * 256 + threadIdx.x;
    lds[threadIdx.x] = (i < N) ? cnt[i] : 0;
    __syncthreads();
    for (int off = 128; off > 0; off >>= 1) {
        if (threadIdx.x < off) lds[threadIdx.x] += lds[threadIdx.x + off];
        __syncthreads();
    }
    if (threadIdx.x == 0) bsum[blockIdx.x] = lds[0];
}

__global__ void bscan_kernel(int* __restrict__ bsum, int* __restrict__ row_ptr, int nb, int N) {
    __shared__ int lds[256];
    int t = threadIdx.x;
    int v = (t < nb) ? bsum[t] : 0;
    lds[t] = v;
    __syncthreads();
    for (int off = 1; off < 256; off <<= 1) {
        int a = lds[t];
        int b = (t >= off) ? lds[t - off] : 0;
        __syncthreads();
        lds[t] = a + b;
        __syncthreads();
    }
    if (t < nb) bsum[t] = lds[t] - v;
    if (t == 0) row_ptr[N] = lds[255];
}

__global__ void chunk_scan_kernel(const int* __restrict__ cnt, const int* __restrict__ bsum,
                                  int* __restrict__ row_ptr, float* __restrict__ dinv, int N) {
    __shared__ int lds[256];
    int t = threadIdx.x;
    int i = blockIdx.x * 256 + t;
    int v = (i < N) ? cnt[i] : 0;
    lds[t] = v;
    __syncthreads();
    for (int off = 1; off < 256; off <<= 1) {
        int a = lds[t];
        int b = (t >= off) ? lds[t - off] : 0;
        __syncthreads();
        lds[t] = a + b;
        __syncthreads();
    }
    if (i < N) {
        row_ptr[i] = bsum[blockIdx.x] + lds[t] - v;
        dinv[i]    = rsqrtf((float)v + 1.0f);
    }
}

__global__ void off2_scan(const int* __restrict__ cnt2T, const int* __restrict__ row_ptr,
                          int* __restrict__ off2T, int nchunks) {
    __shared__ int lds[256];
    int b = blockIdx.x, t = threadIdx.x;
    int v = (t < nchunks) ? cnt2T[b * nchunks + t] : 0;
    lds[t] = v;
    __syncthreads();
    for (int off = 1; off < 256; off <<= 1) {
        int a = lds[t];
        int s = (t >= off) ? lds[t - off] : 0;
        __syncthreads();
        lds[t] = a + s;
        __syncthreads();
    }
    if (t < nchunks) off2T[b * nchunks + t] = row_ptr[b * 256] + lds[t] - v;
}

__global__ void binpass(const int* __restrict__ src, const int* __restrict__ dst,
                        const float* __restrict__ dinv, const int* __restrict__ off2T,
                        int2* __restrict__ tmp, int E, int nbuckets, int nchunks) {
    __shared__ int cur[256];
    int t = threadIdx.x, c = blockIdx.x;
    if (t < 256) cur[t] = (t < nbuckets) ? off2T[t * nchunks + c] : 0;
    __syncthreads();
    int base = c * 4096;
    #pragma unroll
    for (int j = 0; j < 4; j++) {
        int e = base + t + j * 1024;
        if (e < E) {
            int s = src[e], d = dst[e];
            float w = dinv[s] * dinv[d];
            int slot = atomicAdd(&cur[d >> 8], 1);
            unsigned packed = ((unsigned)s << 16) | (unsigned)f2bf(w);
            tmp[slot] = make_int2(d, (int)packed);
        }
    }
}

__global__ void csr_build(const int2* __restrict__ tmp, const int* __restrict__ row_ptr,
                          unsigned* __restrict__ csr, int N) {
    __shared__ unsigned staged[STAGE_CAP];
    __shared__ int curL[256];
    int b = blockIdx.x, t = threadIdx.x;
    int node0 = b * 256;
    int nodeEnd = min(node0 + 256, N);
    int segBase = row_ptr[node0];
    int segEnd  = row_ptr[nodeEnd];
    if (t < 256) {
        int n = node0 + t;
        curL[t] = (n < nodeEnd) ? (row_ptr[n] - segBase) : 0;
    }
    __syncthreads();
    int segLen = segEnd - segBase;
    for (int i = t; i < segLen; i += 1024) {
        int2 en = tmp[segBase + i];
        int local = en.x - node0;
        int idx = atomicAdd(&curL[local], 1);
        if (idx < STAGE_CAP) staged[idx] = (unsigned)en.y;
        else csr[segBase + idx] = (unsigned)en.y;
    }
    __syncthreads();
    for (int i = t; i < segLen && i < STAGE_CAP; i += 1024)
        csr[segBase + i] = staged[i];
}

// ================= layer 1: pad x (bf16), aggregate, matmul =================

__global__ void pad_x(const float* __restrict__ x, unsigned short* __restrict__ xp, int N) {
    int idx = blockIdx.x * 256 + threadIdx.x;
    if (idx >= N * 16) return;
    int n = idx >> 4, c = idx & 15;
    xp[idx] = (c < FEAT) ? f2bf(x[n * FEAT + c]) : (unsigned short)0;
}

// aggx[n][16] fp32 = wself*xp[n] + sum_e w_e * xp[src_e]; 2 lanes/node, 8 bf16 per lane.
__global__ void gather_x(const int* __restrict__ row_ptr, const unsigned* __restrict__ csr,
                         const unsigned short* __restrict__ xp, const float* __restrict__ dinv,
                         float* __restrict__ aggx, int N) {
    int t = threadIdx.x;
    int node = blockIdx.x * 128 + (t >> 1);
    if (node >= N) return;
    int q = t & 1;
    int c0 = q * 8;
    float acc[8] = {0.f,0.f,0.f,0.f,0.f,0.f,0.f,0.f};
    float di = dinv[node];
    uint4 sv = *(const uint4*)(xp + (size_t)node * 16 + c0);
    bf8_fma(acc, sv, di * di);
    int i = row_ptr[node], i1 = row_ptr[node + 1];
    for (; i + 8 <= i1; i += 8) {
        unsigned e0 = csr[i], e1 = csr[i+1], e2 = csr[i+2], e3 = csr[i+3];
        unsigned e4 = csr[i+4], e5 = csr[i+5], e6 = csr[i+6], e7 = csr[i+7];
        uint4 u0 = *(const uint4*)(xp + (size_t)csr_src(e0) * 16 + c0);
        uint4 u1 = *(const uint4*)(xp + (size_t)csr_src(e1) * 16 + c0);
        uint4 u2 = *(const uint4*)(xp + (size_t)csr_src(e2) * 16 + c0);
        uint4 u3 = *(const uint4*)(xp + (size_t)csr_src(e3) * 16 + c0);
        uint4 u4 = *(const uint4*)(xp + (size_t)csr_src(e4) * 16 + c0);
        uint4 u5 = *(const uint4*)(xp + (size_t)csr_src(e5) * 16 + c0);
        uint4 u6 = *(const uint4*)(xp + (size_t)csr_src(e6) * 16 + c0);
        uint4 u7 = *(const uint4*)(xp + (size_t)csr_src(e7) * 16 + c0);
        bf8_fma(acc, u0, csr_w(e0));
        bf8_fma(acc, u1, csr_w(e1));
        bf8_fma(acc, u2, csr_w(e2));
        bf8_fma(acc, u3, csr_w(e3));
        bf8_fma(acc, u4, csr_w(e4));
        bf8_fma(acc, u5, csr_w(e5));
        bf8_fma(acc, u6, csr_w(e6));
        bf8_fma(acc, u7, csr_w(e7));
    }
    for (; i < i1; i++) {
        unsigned e0 = csr[i];
        uint4 u0 = *(const uint4*)(xp + (size_t)csr_src(e0) * 16 + c0);
        bf8_fma(acc, u0, csr_w(e0));
    }
    float4 o0 = make_float4(acc[0], acc[1], acc[2], acc[3]);
    float4 o1 = make_float4(acc[4], acc[5], acc[6], acc[7]);
    *(float4*)(aggx + (size_t)node * 16 + c0)     = o0;
    *(float4*)(aggx + (size_t)node * 16 + c0 + 4) = o1;
}

// h1 = relu(aggx @ W1 + b1), fp32. 64 nodes/block, 4 nodes x 4 cols per thread.
__global__ void gcn_matmul1(const float* __restrict__ aggx, const float* __restrict__ W1,
                            const float* __restrict__ b1, float* __restrict__ h1, int N) {
    __shared__ float sW[FEAT * 64];
    __shared__ float sH[64 * 16];
    int t = threadIdx.x;
    int node0 = blockIdx.x * 64;
    for (int i = t; i < FEAT * 64; i += 256) sW[i] = W1[i];
    for (int i = t; i < 64 * 16; i += 256) {
        int r = i >> 4, k = i & 15;
        int node = node0 + r;
        sH[i] = (node < N) ? aggx[(size_t)node * 16 + k] : 0.0f;
    }
    __syncthreads();
    int c0 = (t & 15) * 4;
    int rbase = (t >> 4) * 4;
    float4 a0 = {0,0,0,0}, a1 = {0,0,0,0}, a2 = {0,0,0,0}, a3 = {0,0,0,0};
    for (int k = 0; k < FEAT; k++) {
        float4 w = *(const float4*)(sW + k * 64 + c0);
        float h0 = sH[(rbase + 0) * 16 + k];
        float h1v = sH[(rbase + 1) * 16 + k];
        float h2 = sH[(rbase + 2) * 16 + k];
        float h3 = sH[(rbase + 3) * 16 + k];
        a0.x += h0 * w.x; a0.y += h0 * w.y; a0.z += h0 * w.z; a0.w += h0 * w.w;
        a1.x += h1v * w.x; a1.y += h1v * w.y; a1.z += h1v * w.z; a1.w += h1v * w.w;
        a2.x += h2 * w.x; a2.y += h2 * w.y; a2.z += h2 * w.z; a2.w += h2 * w.w;
        a3.x += h3 * w.x; a3.y += h3 * w.y; a3.z += h3 * w.z; a3.w += h3 * w.w;
    }
    float4 bb = *(const float4*)(b1 + c0);
    float4 accs[4] = {a0, a1, a2, a3};
    for (int rr = 0; rr < 4; rr++) {
        int node = node0 + rbase + rr;
        if (node >= N) break;
        float4 v = accs[rr];
        v.x = fmaxf(v.x + bb.x, 0.f); v.y = fmaxf(v.y + bb.y, 0.f);
        v.z = fmaxf(v.z + bb.z, 0.f); v.w = fmaxf(v.w + bb.w, 0.f);
        *(float4*)(h1 + (size_t)node * 64 + c0) = v;
    }
}

// ================= layers 2/3 =================

// hwb (4 slices of 16 cols) = bf16(h_in @ W): hwb[slice][node][16]. 64 nodes/block.
__global__ void gcn_matmul64(const float* __restrict__ h_in, const float* __restrict__ W,
                             unsigned short* __restrict__ hwb, int N) {
    __shared__ float sW[64 * 64];
    __shared__ float sH[64 * 65];
    int t = threadIdx.x;
    int node0 = blockIdx.x * 64;
    for (int i = t * 4; i < 4096; i += 1024)
        *(float4*)(sW + i) = *(const float4*)(W + i);
    for (int i = t; i < 4096; i += 256) {
        int r = i >> 6, k = i & 63;
        int node = node0 + r;
        sH[r * 65 + k] = (node < N) ? h_in[(size_t)node * 64 + k] : 0.0f;
    }
    __syncthreads();
    int c0 = (t & 15) * 4;
    int rbase = (t >> 4) * 4;
    float4 a0 = {0,0,0,0}, a1 = {0,0,0,0}, a2 = {0,0,0,0}, a3 = {0,0,0,0};
    for (int k = 0; k < 64; k++) {
        float4 w = *(const float4*)(sW + k * 64 + c0);
        float h0 = sH[(rbase + 0) * 65 + k];
        float h1v = sH[(rbase + 1) * 65 + k];
        float h2 = sH[(rbase + 2) * 65 + k];
        float h3 = sH[(rbase + 3) * 65 + k];
        a0.x += h0 * w.x; a0.y += h0 * w.y; a0.z += h0 * w.z; a0.w += h0 * w.w;
        a1.x += h1v * w.x; a1.y += h1v * w.y; a1.z += h1v * w.z; a1.w += h1v * w.w;
        a2.x += h2 * w.x; a2.y += h2 * w.y; a2.z += h2 * w.z; a2.w += h2 * w.w;
        a3.x += h3 * w.x; a3.y += h3 * w.y; a3.z += h3 * w.z; a3.w += h3 * w.w;
    }
    int slice = c0 >> 4;
    int cin   = c0 & 15;
    float4 accs[4] = {a0, a1, a2, a3};
    for (int rr = 0; rr < 4; rr++) {
        int node = node0 + rbase + rr;
        if (node >= N) break;
        float4 v = accs[rr];
        ushort4 o;
        o.x = f2bf(v.x); o.y = f2bf(v.y); o.z = f2bf(v.z); o.w = f2bf(v.w);
        *(ushort4*)(hwb + ((size_t)slice * N + node) * 16 + cin) = o;
    }
}

// XCD-swizzled slice gather: slice = blockIdx % 4 (16 cols, 1.6 MB working set).
// With blockIdx%8 -> XCD round-robin, each XCD touches exactly one slice.
// 128 nodes/block, 2 lanes/node, 8 bf16 (16 B) per lane.
__global__ void gather_bf(const int* __restrict__ row_ptr, const unsigned* __restrict__ csr,
                          const unsigned short* __restrict__ hwb,
                          const float* __restrict__ dinv, const float* __restrict__ b,
                          float* __restrict__ out, float* __restrict__ gsum,
                          int N, int do_gsum) {
    int t = threadIdx.x;
    int slice = blockIdx.x & 3;
    int nodeBlk = blockIdx.x >> 2;
    int nl = t >> 1;                 // 0..127
    int node = nodeBlk * 128 + nl;
    int q = t & 1;
    int c0 = q * 8;
    const unsigned short* hb = hwb + (size_t)slice * N * 16;
    float acc[8] = {0.f,0.f,0.f,0.f,0.f,0.f,0.f,0.f};
    if (node < N) {
        float di = dinv[node];
        uint4 sv = *(const uint4*)(hb + (size_t)node * 16 + c0);
        bf8_fma(acc, sv, di * di);
        int i = row_ptr[node], i1 = row_ptr[node + 1];
        for (; i + 8 <= i1; i += 8) {
            unsigned e0 = csr[i], e1 = csr[i+1], e2 = csr[i+2], e3 = csr[i+3];
            unsigned e4 = csr[i+4], e5 = csr[i+5], e6 = csr[i+6], e7 = csr[i+7];
            uint4 u0 = *(const uint4*)(hb + (size_t)csr_src(e0) * 16 + c0);
            uint4 u1 = *(const uint4*)(hb + (size_t)csr_src(e1) * 16 + c0);
            uint4 u2 = *(const uint4*)(hb + (size_t)csr_src(e2) * 16 + c0);
            uint4 u3 = *(const uint4*)(hb + (size_t)csr_src(e3) * 16 + c0);
            uint4 u4 = *(const uint4*)(hb + (size_t)csr_src(e4) * 16 + c0);
            uint4 u5 = *(const uint4*)(hb + (size_t)csr_src(e5) * 16 + c0);
            uint4 u6 = *(const uint4*)(hb + (size_t)csr_src(e6) * 16 + c0);
            uint4 u7 = *(const uint4*)(hb + (size_t)csr_src(e7) * 16 + c0);
            bf8_fma(acc, u0, csr_w(e0));
            bf8_fma(acc, u1, csr_w(e1));
            bf8_fma(acc, u2, csr_w(e2));
            bf8_fma(acc, u3, csr_w(e3));
            bf8_fma(acc, u4, csr_w(e4));
            bf8_fma(acc, u5, csr_w(e5));
            bf8_fma(acc, u6, csr_w(e6));
            bf8_fma(acc, u7, csr_w(e7));
        }
        for (; i < i1; i++) {
            unsigned e0 = csr[i];
            uint4 u0 = *(const uint4*)(hb + (size_t)csr_src(e0) * 16 + c0);
            bf8_fma(acc, u0, csr_w(e0));
        }
        int cg = slice * 16 + c0;
        const float4 bb0 = *(const float4*)(b + cg);
        const float4 bb1 = *(const float4*)(b + cg + 4);
        float4 o0, o1;
        o0.x = fmaxf(acc[0] + bb0.x, 0.f); o0.y = fmaxf(acc[1] + bb0.y, 0.f);
        o0.z = fmaxf(acc[2] + bb0.z, 0.f); o0.w = fmaxf(acc[3] + bb0.w, 0.f);
        o1.x = fmaxf(acc[4] + bb1.x, 0.f); o1.y = fmaxf(acc[5] + bb1.y, 0.f);
        o1.z = fmaxf(acc[6] + bb1.z, 0.f); o1.w = fmaxf(acc[7] + bb1.w, 0.f);
        *(float4*)(out + (size_t)node * 64 + cg)     = o0;
        *(float4*)(out + (size_t)node * 64 + cg + 4) = o1;
        acc[0]=o0.x; acc[1]=o0.y; acc[2]=o0.z; acc[3]=o0.w;
        acc[4]=o1.x; acc[5]=o1.y; acc[6]=o1.z; acc[7]=o1.w;
    } else {
        for (int j = 0; j < 8; j++) acc[j] = 0.f;
    }
    if (do_gsum) {
        __shared__ float red[128 * 16];
        for (int j = 0; j < 8; j++) red[nl * 16 + c0 + j] = acc[j];
        __syncthreads();
        if (t < 16) {
            float s = 0.f;
            for (int k = 0; k < 128; k++) s += red[k * 16 + t];
            atomicAdd(&gsum[slice * 16 + t], s);
        }
    }
}

// ================= head =================

__global__ void final_kernel(const float* __restrict__ h3, const int* __restrict__ sheet_idx,
                             const float* __restrict__ sheet_feat, const float* __restrict__ g_sum,
                             const float* __restrict__ gW1, const float* __restrict__ gb1,
                             const float* __restrict__ gW2, const float* __restrict__ gb2,
                             const float* __restrict__ fW,  const float* __restrict__ fb,
                             const float* __restrict__ qW1, const float* __restrict__ qb1,
                             const float* __restrict__ qW2, const float* __restrict__ qb2,
                             float* __restrict__ out, int N, int L) {
    int s = blockIdx.x, t = threadIdx.x;
    __shared__ float red[256];
    __shared__ float semb[64];
    __shared__ float geoh[64];
    __shared__ float geo[64];
    __shared__ float hq[128];
    int c = t & 63, jg = t >> 6;
    float acc = 0.0f;
    for (int j = jg; j < L; j += 4) {
        int node = sheet_idx[s * L + j];
        acc += h3[(size_t)node * 64 + c];
    }
    red[t] = acc;
    __syncthreads();
    if (t < 64) {
        semb[t] = (red[t] + red[t + 64] + red[t + 128] + red[t + 192]) / (float)L;
        hq[64 + t] = g_sum[t] / (float)N;
        float a = gb1[t];
        #pragma unroll
        for (int k = 0; k < FEAT; k++) a += sheet_feat[s * FEAT + k] * gW1[k * 64 + t];
        geoh[t] = fmaxf(a, 0.0f);
    }
    __syncthreads();
    if (t < 64) {
        float a = gb2[t];
        for (int k = 0; k < 64; k++) a += geoh[k] * gW2[k * 64 + t];
        geo[t] = a;
    }
    __syncthreads();
    if (t < 64) {
        float a = fb[t];
        for (int k = 0; k < 64; k++) a += semb[k] * fW[k * 64 + t];
        for (int k = 0; k < 64; k++) a += geo[k]  * fW[(64 + k) * 64 + t];
        hq[t] = fmaxf(a, 0.0f);
    }
    __syncthreads();
    float q = 0.0f;
    if (t < 64) {
        float a = qb1[t];
        for (int k = 0; k < 128; k++) a += hq[k] * qW1[k * 64 + t];
        a = fmaxf(a, 0.0f);
        q = a * qW2[t];
        for (int off = 32; off > 0; off >>= 1) q += __shfl_down(q, off, 64);
        if (t == 0) out[s] = q + qb2[0];
    }
}

extern "C" void kernel_launch(void* const* d_in, const int* in_sizes, int n_in,
                              void* d_out, int out_size, void* d_ws, size_t ws_size,
                              hipStream_t stream) {
    const float* x          = (const float*)d_in[0];
    const int*   edge       = (const int*)d_in[1];
    const int*   sheet_idx  = (const int*)d_in[3];
    const float* sheet_feat = (const float*)d_in[4];
    const float* W1 = (const float*)d_in[5];  const float* b1 = (const float*)d_in[6];
    const float* W2 = (const float*)d_in[7];  const float* b2 = (const float*)d_in[8];
    const float* W3 = (const float*)d_in[9];  const float* b3 = (const float*)d_in[10];
    const float* gW1 = (const float*)d_in[11]; const float* gb1 = (const float*)d_in[12];
    const float* gW2 = (const float*)d_in[13]; const float* gb2 = (const float*)d_in[14];
    const float* fW  = (const float*)d_in[15]; const float* fb  = (const float*)d_in[16];
    const float* qW1 = (const float*)d_in[17]; const float* qb1 = (const float*)d_in[18];
    const float* qW2 = (const float*)d_in[19]; const float* qb2 = (const float*)d_in[20];
    float* out = (float*)d_out;

    int N = in_sizes[2];            // 50000
    int E = in_sizes[1] / 2;        // 800000
    int S = in_sizes[4] / FEAT;     // 256
    int L = in_sizes[3] / S;        // 128

    int nb       = (N + 255) / 256;     // 196 scan blocks (<=256 required)
    int nbuckets = (N + 255) / 256;     // 196 (requires N <= 65536 for u16 src)
    int nchunks  = (E + 4095) / 4096;   // 196 (<=256 required for off2_scan)

    // ---- workspace layout (16B-aligned big blocks first) ----
    char* p = (char*)d_ws;
    int2*  tmp     = (int2*)p;                 p += (size_t)E * 8;              // 6.4 MB
    unsigned* csr  = (unsigned*)p;             p += (size_t)E * 4;              // 3.2 MB
    float* hf      = (float*)p;                p += (size_t)N * 64 * 4;         // 12.8 MB
    unsigned short* hwb = (unsigned short*)p;  p += (size_t)N * 64 * 2;         // 6.4 MB
    unsigned short* xp  = (unsigned short*)p;  p += (size_t)N * 16 * 2;         // 1.6 MB
    float* aggx    = (float*)p;                p += (size_t)N * 16 * 4;         // 3.2 MB
    int*   cnt     = (int*)p;                  p += (size_t)N * 4;
    int*   row_ptr = (int*)p;                  p += (size_t)(N + 1) * 4;
    int*   bsum    = (int*)p;                  p += 256 * 4;
    float* dinv    = (float*)p;                p += (size_t)N * 4;
    float* gsum    = (float*)p;                p += 64 * 4;
    int*   cnt2T   = (int*)p;                  p += (size_t)nbuckets * nchunks * 4;
    int*   off2T   = (int*)p;                  /* nbuckets*nchunks*4 */

    hipMemsetAsync(cnt, 0, (size_t)N * 4, stream);
    hipMemsetAsync(gsum, 0, 64 * 4, stream);

    const int* src = edge;
    const int* dst = edge + E;

    int gMM = (N + 63) / 64;
    int nodeBlocks = (N + 127) / 128;
    int gGB = 4 * nodeBlocks;          // 4 slices interleaved via blockIdx % 4
    int gGX = nodeBlocks;
    int gPX = (N * 16 + 255) / 256;

    // CSR build (bucketed, coalesced writes; parallel offset scan)
    histA<<<nchunks, 1024, 0, stream>>>(dst, cnt, cnt2T, E, nbuckets, nchunks);
    bsum_kernel<<<nb, 256, 0, stream>>>(cnt, bsum, N);
    bscan_kernel<<<1, 256, 0, stream>>>(bsum, row_ptr, nb, N);
    chunk_scan_kernel<<<nb, 256, 0, stream>>>(cnt, bsum, row_ptr, dinv, N);
    off2_scan<<<nbuckets, 256, 0, stream>>>(cnt2T, row_ptr, off2T, nchunks);
    binpass<<<nchunks, 1024, 0, stream>>>(src, dst, dinv, off2T, tmp, E, nbuckets, nchunks);
    csr_build<<<nbuckets, 1024, 0, stream>>>(tmp, row_ptr, csr, N);

    // layer 1 (linear trick): pad x (bf16), aggregate, matmul -> hf (h1)
    pad_x<<<gPX, 256, 0, stream>>>(x, xp, N);
    gather_x<<<gGX, 256, 0, stream>>>(row_ptr, csr, xp, dinv, aggx, N);
    gcn_matmul1<<<gMM, 256, 0, stream>>>(aggx, W1, b1, hf, N);

    // layer 2: hf @ W2 -> hwb (bf16, 4 slices); gather -> hf (h2)
    gcn_matmul64<<<gMM, 256, 0, stream>>>(hf, W2, hwb, N);
    gather_bf<<<gGB, 256, 0, stream>>>(row_ptr, csr, hwb, dinv, b2, hf, gsum, N, 0);

    // layer 3: hf @ W3 -> hwb; gather -> hf (h3) + gsum
    gcn_matmul64<<<gMM, 256, 0, stream>>>(hf, W3, hwb, N);
    gather_bf<<<gGB, 256, 0, stream>>>(row_ptr, csr, hwb, dinv, b3, hf, gsum, N, 1);

    final_kernel<<<S, 256, 0, stream>>>(hf, sheet_idx, sheet_feat, gsum,
                                        gW1, gb1, gW2, gb2, fW, fb,
                                        qW1, qb1, qW2, qb2, out, N, L);
}

// Round 9
// 241.914 us; speedup vs baseline: 1.2739x; 1.2739x over previous
//
#include <hip/hip_runtime.h>

#define HID 64
#define FEAT 10
#define MAXSEG 8192        // padded csr segment per 256-node bucket (mean 4096+pad<6900)

typedef unsigned short u16;

// ---------- helpers ----------
__device__ inline u16 f2bf(float f) {                     // fp32 -> bf16 RNE
    unsigned u = __float_as_uint(f);
    unsigned r = (u + 0x7fffu + ((u >> 16) & 1u)) >> 16;
    return (u16)r;
}
// decode 8 bf16 (uint4) and add into acc[8] (no weight: weights factored into hwb)
__device__ inline void bf8_add(float* acc, uint4 u) {
    acc[0] += __uint_as_float(u.x << 16);
    acc[1] += __uint_as_float(u.x & 0xffff0000u);
    acc[2] += __uint_as_float(u.y << 16);
    acc[3] += __uint_as_float(u.y & 0xffff0000u);
    acc[4] += __uint_as_float(u.z << 16);
    acc[5] += __uint_as_float(u.z & 0xffff0000u);
    acc[6] += __uint_as_float(u.w << 16);
    acc[7] += __uint_as_float(u.w & 0xffff0000u);
}

// ================= CSR build =================

__global__ void histA(const int* __restrict__ dst, int* __restrict__ cnt2T,
                      int E, int nbuckets, int nchunks) {
    __shared__ int lh[256];
    int t = threadIdx.x, c = blockIdx.x;
    if (t < 256) lh[t] = 0;
    __syncthreads();
    int base = c * 4096;
    #pragma unroll
    for (int j = 0; j < 4; j++) {
        int e = base + t + j * 1024;
        if (e < E) atomicAdd(&lh[dst[e] >> 8], 1);
    }
    __syncthreads();
    if (t < nbuckets) cnt2T[t * nchunks + c] = lh[t];
}

__global__ void off2_local(const int* __restrict__ cnt2T, int* __restrict__ off2L,
                           int* __restrict__ tot, int nchunks) {
    __shared__ int lds[256];
    int b = blockIdx.x, t = threadIdx.x;
    int v = (t < nchunks) ? cnt2T[b * nchunks + t] : 0;
    lds[t] = v;
    __syncthreads();
    for (int off = 1; off < 256; off <<= 1) {
        int a = lds[t];
        int s = (t >= off) ? lds[t - off] : 0;
        __syncthreads();
        lds[t] = a + s;
        __syncthreads();
    }
    if (t < nchunks) off2L[b * nchunks + t] = lds[t] - v;
    if (t == 255) tot[b] = lds[255];
}

__global__ void base_scan(const int* __restrict__ tot, int* __restrict__ base, int nbuckets) {
    __shared__ int lds[256];
    int t = threadIdx.x;
    int v = (t < nbuckets) ? tot[t] : 0;
    lds[t] = v;
    __syncthreads();
    for (int off = 1; off < 256; off <<= 1) {
        int a = lds[t];
        int s = (t >= off) ? lds[t - off] : 0;
        __syncthreads();
        lds[t] = a + s;
        __syncthreads();
    }
    if (t < nbuckets) base[t] = lds[t] - v;
}

__global__ void binpass(const int* __restrict__ src, const int* __restrict__ dst,
                        const int* __restrict__ base, const int* __restrict__ off2L,
                        unsigned* __restrict__ tmp, int E, int nbuckets, int nchunks) {
    __shared__ int cur[256];
    int t = threadIdx.x, c = blockIdx.x;
    if (t < 256) cur[t] = (t < nbuckets) ? base[t] + off2L[t * nchunks + c] : 0;
    __syncthreads();
    int b0 = c * 4096;
    #pragma unroll
    for (int j = 0; j < 4; j++) {
        int e = b0 + t + j * 1024;
        if (e < E) {
            int s = src[e], d = dst[e];
            int slot = atomicAdd(&cur[d >> 8], 1);
            tmp[slot] = ((unsigned)(d & 255) << 16) | (unsigned)s;
        }
    }
}

__global__ void csr_build(const unsigned* __restrict__ tmp, const int* __restrict__ base,
                          const int* __restrict__ tot, u16* __restrict__ csr2,
                          int* __restrict__ row_start, int* __restrict__ row_cntp,
                          float* __restrict__ dinv, int N) {
    __shared__ __align__(16) u16 staged[MAXSEG];
    __shared__ int cntL[256], padL[256], scanL[256], curL[256];
    int b = blockIdx.x, t = threadIdx.x;          // 1024 threads
    if (t < 256) cntL[t] = 0;
    for (int i = t; i < MAXSEG; i += 1024) staged[i] = (u16)N;   // sentinel prefill
    __syncthreads();
    int segBase = base[b], segLen = tot[b];
    for (int i = t; i < segLen; i += 1024)
        atomicAdd(&cntL[tmp[segBase + i] >> 16], 1);
    __syncthreads();
    if (t < 256) { padL[t] = (cntL[t] + 7) & ~7; scanL[t] = padL[t]; }
    __syncthreads();
    for (int off = 1; off < 256; off <<= 1) {
        int a = (t < 256) ? scanL[t] : 0;
        int s = (t >= off && t < 256) ? scanL[t - off] : 0;
        __syncthreads();
        if (t < 256) scanL[t] = a + s;
        __syncthreads();
    }
    if (t < 256) {
        int excl = scanL[t] - padL[t];
        curL[t] = excl;
        int node = b * 256 + t;
        if (node < N) {
            row_start[node] = b * MAXSEG + excl;
            row_cntp[node]  = padL[t];
            dinv[node]      = rsqrtf((float)cntL[t] + 1.0f);
        }
    }
    __syncthreads();
    for (int i = t; i < segLen; i += 1024) {
        unsigned e = tmp[segBase + i];
        int idx = atomicAdd(&curL[e >> 16], 1);
        staged[idx] = (u16)(e & 0xffffu);
    }
    __syncthreads();
    ((uint4*)(csr2 + (size_t)b * MAXSEG))[t] = ((const uint4*)staged)[t];
}

__global__ void zero_sentinel(u16* __restrict__ hwb, u16* __restrict__ xp, int N) {
    int t = threadIdx.x;
    if (t < 64) hwb[((size_t)(t >> 4) * (N + 1) + N) * 16 + (t & 15)] = 0;
    else if (t < 80) xp[(size_t)N * 16 + (t - 64)] = 0;
}

// ================= layer 1 =================

__global__ void pad_x(const float* __restrict__ x, const float* __restrict__ dinv,
                      u16* __restrict__ xp, int N) {
    int idx = blockIdx.x * 256 + threadIdx.x;
    if (idx >= N * 16) return;
    int n = idx >> 4, c = idx & 15;
    xp[idx] = (c < FEAT) ? f2bf(dinv[n] * x[n * FEAT + c]) : (u16)0;
}

__global__ void gather_x(const int* __restrict__ row_start, const int* __restrict__ row_cntp,
                         const u16* __restrict__ csr2, const u16* __restrict__ xp,
                         const float* __restrict__ dinv, float* __restrict__ aggx, int N) {
    int t = threadIdx.x;
    int node = blockIdx.x * 128 + (t >> 1);
    if (node >= N) return;
    int c0 = (t & 1) * 8;
    float acc[8] = {0.f,0.f,0.f,0.f,0.f,0.f,0.f,0.f};
    uint4 sv = *(const uint4*)(xp + (size_t)node * 16 + c0);
    bf8_add(acc, sv);
    int i0 = row_start[node], iE = i0 + row_cntp[node];
    for (int i = i0; i < iE; i += 8) {
        uint4 ev = *(const uint4*)(csr2 + i);
        int s0 = ev.x & 0xffff, s1 = ev.x >> 16;
        int s2 = ev.y & 0xffff, s3 = ev.y >> 16;
        int s4 = ev.z & 0xffff, s5 = ev.z >> 16;
        int s6 = ev.w & 0xffff, s7 = ev.w >> 16;
        uint4 u0 = *(const uint4*)(xp + (size_t)s0 * 16 + c0);
        uint4 u1 = *(const uint4*)(xp + (size_t)s1 * 16 + c0);
        uint4 u2 = *(const uint4*)(xp + (size_t)s2 * 16 + c0);
        uint4 u3 = *(const uint4*)(xp + (size_t)s3 * 16 + c0);
        uint4 u4 = *(const uint4*)(xp + (size_t)s4 * 16 + c0);
        uint4 u5 = *(const uint4*)(xp + (size_t)s5 * 16 + c0);
        uint4 u6 = *(const uint4*)(xp + (size_t)s6 * 16 + c0);
        uint4 u7 = *(const uint4*)(xp + (size_t)s7 * 16 + c0);
        bf8_add(acc, u0); bf8_add(acc, u1); bf8_add(acc, u2); bf8_add(acc, u3);
        bf8_add(acc, u4); bf8_add(acc, u5); bf8_add(acc, u6); bf8_add(acc, u7);
    }
    float di = dinv[node];
    float4 o0 = make_float4(acc[0]*di, acc[1]*di, acc[2]*di, acc[3]*di);
    float4 o1 = make_float4(acc[4]*di, acc[5]*di, acc[6]*di, acc[7]*di);
    *(float4*)(aggx + (size_t)node * 16 + c0)     = o0;
    *(float4*)(aggx + (size_t)node * 16 + c0 + 4) = o1;
}

__global__ void gcn_matmul1(const float* __restrict__ aggx, const float* __restrict__ W1,
                            const float* __restrict__ b1, float* __restrict__ h1, int N) {
    __shared__ float sW[FEAT * 64];
    __shared__ float sH[64 * 16];
    int t = threadIdx.x;
    int node0 = blockIdx.x * 64;
    for (int i = t; i < FEAT * 64; i += 256) sW[i] = W1[i];
    for (int i = t; i < 64 * 16; i += 256) {
        int r = i >> 4, k = i & 15;
        int node = node0 + r;
        sH[i] = (node < N) ? aggx[(size_t)node * 16 + k] : 0.0f;
    }
    __syncthreads();
    int c0 = (t & 15) * 4;
    int rbase = (t >> 4) * 4;
    float4 a0 = {0,0,0,0}, a1 = {0,0,0,0}, a2 = {0,0,0,0}, a3 = {0,0,0,0};
    for (int k = 0; k < FEAT; k++) {
        float4 w = *(const float4*)(sW + k * 64 + c0);
        float h0 = sH[(rbase + 0) * 16 + k];
        float h1v = sH[(rbase + 1) * 16 + k];
        float h2 = sH[(rbase + 2) * 16 + k];
        float h3 = sH[(rbase + 3) * 16 + k];
        a0.x += h0 * w.x; a0.y += h0 * w.y; a0.z += h0 * w.z; a0.w += h0 * w.w;
        a1.x += h1v * w.x; a1.y += h1v * w.y; a1.z += h1v * w.z; a1.w += h1v * w.w;
        a2.x += h2 * w.x; a2.y += h2 * w.y; a2.z += h2 * w.z; a2.w += h2 * w.w;
        a3.x += h3 * w.x; a3.y += h3 * w.y; a3.z += h3 * w.z; a3.w += h3 * w.w;
    }
    float4 bb = *(const float4*)(b1 + c0);
    float4 accs[4] = {a0, a1, a2, a3};
    for (int rr = 0; rr < 4; rr++) {
        int node = node0 + rbase + rr;
        if (node >= N) break;
        float4 v = accs[rr];
        v.x = fmaxf(v.x + bb.x, 0.f); v.y = fmaxf(v.y + bb.y, 0.f);
        v.z = fmaxf(v.z + bb.z, 0.f); v.w = fmaxf(v.w + bb.w, 0.f);
        *(float4*)(h1 + (size_t)node * 64 + c0) = v;
    }
}

// ================= layers 2/3 =================

__global__ void gcn_matmul64(const float* __restrict__ h_in, const float* __restrict__ W,
                             const float* __restrict__ dinv, u16* __restrict__ hwb, int N) {
    __shared__ float sW[64 * 64];
    __shared__ float sH[64 * 65];
    int t = threadIdx.x;
    int node0 = blockIdx.x * 64;
    for (int i = t * 4; i < 4096; i += 1024)
        *(float4*)(sW + i) = *(const float4*)(W + i);
    for (int i = t; i < 4096; i += 256) {
        int r = i >> 6, k = i & 63;
        int node = node0 + r;
        sH[r * 65 + k] = (node < N) ? h_in[(size_t)node * 64 + k] : 0.0f;
    }
    __syncthreads();
    int c0 = (t & 15) * 4;
    int rbase = (t >> 4) * 4;
    float4 a0 = {0,0,0,0}, a1 = {0,0,0,0}, a2 = {0,0,0,0}, a3 = {0,0,0,0};
    for (int k = 0; k < 64; k++) {
        float4 w = *(const float4*)(sW + k * 64 + c0);
        float h0 = sH[(rbase + 0) * 65 + k];
        float h1v = sH[(rbase + 1) * 65 + k];
        float h2 = sH[(rbase + 2) * 65 + k];
        float h3 = sH[(rbase + 3) * 65 + k];
        a0.x += h0 * w.x; a0.y += h0 * w.y; a0.z += h0 * w.z; a0.w += h0 * w.w;
        a1.x += h1v * w.x; a1.y += h1v * w.y; a1.z += h1v * w.z; a1.w += h1v * w.w;
        a2.x += h2 * w.x; a2.y += h2 * w.y; a2.z += h2 * w.z; a2.w += h2 * w.w;
        a3.x += h3 * w.x; a3.y += h3 * w.y; a3.z += h3 * w.z; a3.w += h3 * w.w;
    }
    int slice = c0 >> 4;
    int cin   = c0 & 15;
    float4 accs[4] = {a0, a1, a2, a3};
    for (int rr = 0; rr < 4; rr++) {
        int node = node0 + rbase + rr;
        if (node >= N) break;
        float di = dinv[node];
        float4 v = accs[rr];
        ushort4 o;
        o.x = f2bf(v.x * di); o.y = f2bf(v.y * di);
        o.z = f2bf(v.z * di); o.w = f2bf(v.w * di);
        *(ushort4*)(hwb + ((size_t)slice * (N + 1) + node) * 16 + cin) = o;
    }
}

__global__ void gather_bf(const int* __restrict__ row_start, const int* __restrict__ row_cntp,
                          const u16* __restrict__ csr2, const u16* __restrict__ hwb,
                          const float* __restrict__ dinv, const float* __restrict__ b,
                          float* __restrict__ out, float* __restrict__ gsum,
                          int N, int do_gsum) {
    int t = threadIdx.x;
    int slice = blockIdx.x & 3;
    int nodeBlk = blockIdx.x >> 2;
    int nl = t >> 1;
    int node = nodeBlk * 128 + nl;
    int q = t & 1;
    int c0 = q * 8;
    const u16* hb = hwb + (size_t)slice * (N + 1) * 16;
    float acc[8] = {0.f,0.f,0.f,0.f,0.f,0.f,0.f,0.f};
    if (node < N) {
        uint4 sv = *(const uint4*)(hb + (size_t)node * 16 + c0);
        bf8_add(acc, sv);
        int i0 = row_start[node], iE = i0 + row_cntp[node];
        for (int i = i0; i < iE; i += 8) {
            uint4 ev = *(const uint4*)(csr2 + i);
            int s0 = ev.x & 0xffff, s1 = ev.x >> 16;
            int s2 = ev.y & 0xffff, s3 = ev.y >> 16;
            int s4 = ev.z & 0xffff, s5 = ev.z >> 16;
            int s6 = ev.w & 0xffff, s7 = ev.w >> 16;
            uint4 u0 = *(const uint4*)(hb + (size_t)s0 * 16 + c0);
            uint4 u1 = *(const uint4*)(hb + (size_t)s1 * 16 + c0);
            uint4 u2 = *(const uint4*)(hb + (size_t)s2 * 16 + c0);
            uint4 u3 = *(const uint4*)(hb + (size_t)s3 * 16 + c0);
            uint4 u4 = *(const uint4*)(hb + (size_t)s4 * 16 + c0);
            uint4 u5 = *(const uint4*)(hb + (size_t)s5 * 16 + c0);
            uint4 u6 = *(const uint4*)(hb + (size_t)s6 * 16 + c0);
            uint4 u7 = *(const uint4*)(hb + (size_t)s7 * 16 + c0);
            bf8_add(acc, u0); bf8_add(acc, u1); bf8_add(acc, u2); bf8_add(acc, u3);
            bf8_add(acc, u4); bf8_add(acc, u5); bf8_add(acc, u6); bf8_add(acc, u7);
        }
        float di = dinv[node];
        int cg = slice * 16 + c0;
        const float4 bb0 = *(const float4*)(b + cg);
        const float4 bb1 = *(const float4*)(b + cg + 4);
        float4 o0, o1;
        o0.x = fmaxf(acc[0]*di + bb0.x, 0.f); o0.y = fmaxf(acc[1]*di + bb0.y, 0.f);
        o0.z = fmaxf(acc[2]*di + bb0.z, 0.f); o0.w = fmaxf(acc[3]*di + bb0.w, 0.f);
        o1.x = fmaxf(acc[4]*di + bb1.x, 0.f); o1.y = fmaxf(acc[5]*di + bb1.y, 0.f);
        o1.z = fmaxf(acc[6]*di + bb1.z, 0.f); o1.w = fmaxf(acc[7]*di + bb1.w, 0.f);
        *(float4*)(out + (size_t)node * 64 + cg)     = o0;
        *(float4*)(out + (size_t)node * 64 + cg + 4) = o1;
        acc[0]=o0.x; acc[1]=o0.y; acc[2]=o0.z; acc[3]=o0.w;
        acc[4]=o1.x; acc[5]=o1.y; acc[6]=o1.z; acc[7]=o1.w;
    } else {
        for (int j = 0; j < 8; j++) acc[j] = 0.f;
    }
    if (do_gsum) {
        __shared__ float red[128 * 16];
        for (int j = 0; j < 8; j++) red[nl * 16 + c0 + j] = acc[j];
        __syncthreads();
        if (t < 16) {
            float s = 0.f;
            for (int k = 0; k < 128; k++) s += red[k * 16 + t];
            atomicAdd(&gsum[slice * 16 + t], s);
        }
    }
}

// ================= head =================

__global__ void final_kernel(const float* __restrict__ h3, const int* __restrict__ sheet_idx,
                             const float* __restrict__ sheet_feat, const float* __restrict__ g_sum,
                             const float* __restrict__ gW1, const float* __restrict__ gb1,
                             const float* __restrict__ gW2, const float* __restrict__ gb2,
                             const float* __restrict__ fW,  const float* __restrict__ fb,
                             const float* __restrict__ qW1, const float* __restrict__ qb1,
                             const float* __restrict__ qW2, const float* __restrict__ qb2,
                             float* __restrict__ out, int N, int L) {
    int s = blockIdx.x, t = threadIdx.x;
    __shared__ float red[256];
    __shared__ float semb[64];
    __shared__ float geoh[64];
    __shared__ float geo[64];
    __shared__ float hq[128];
    int c = t & 63, jg = t >> 6;
    float acc = 0.0f;
    for (int j = jg; j < L; j += 4) {
        int node = sheet_idx[s * L + j];
        acc += h3[(size_t)node * 64 + c];
    }
    red[t] = acc;
    __syncthreads();
    if (t < 64) {
        semb[t] = (red[t] + red[t + 64] + red[t + 128] + red[t + 192]) / (float)L;
        hq[64 + t] = g_sum[t] / (float)N;
        float a = gb1[t];
        #pragma unroll
        for (int k = 0; k < FEAT; k++) a += sheet_feat[s * FEAT + k] * gW1[k * 64 + t];
        geoh[t] = fmaxf(a, 0.0f);
    }
    __syncthreads();
    if (t < 64) {
        float a = gb2[t];
        for (int k = 0; k < 64; k++) a += geoh[k] * gW2[k * 64 + t];
        geo[t] = a;
    }
    __syncthreads();
    if (t < 64) {
        float a = fb[t];
        for (int k = 0; k < 64; k++) a += semb[k] * fW[k * 64 + t];
        for (int k = 0; k < 64; k++) a += geo[k]  * fW[(64 + k) * 64 + t];
        hq[t] = fmaxf(a, 0.0f);
    }
    __syncthreads();
    float q = 0.0f;
    if (t < 64) {
        float a = qb1[t];
        for (int k = 0; k < 128; k++) a += hq[k] * qW1[k * 64 + t];
        a = fmaxf(a, 0.0f);
        q = a * qW2[t];
        for (int off = 32; off > 0; off >>= 1) q += __shfl_down(q, off, 64);
        if (t == 0) out[s] = q + qb2[0];
    }
}

extern "C" void kernel_launch(void* const* d_in, const int* in_sizes, int n_in,
                              void* d_out, int out_size, void* d_ws, size_t ws_size,
                              hipStream_t stream) {
    const float* x          = (const float*)d_in[0];
    const int*   edge       = (const int*)d_in[1];
    const int*   sheet_idx  = (const int*)d_in[3];
    const float* sheet_feat = (const float*)d_in[4];
    const float* W1 = (const float*)d_in[5];  const float* b1 = (const float*)d_in[6];
    const float* W2 = (const float*)d_in[7];  const float* b2 = (const float*)d_in[8];
    const float* W3 = (const float*)d_in[9];  const float* b3 = (const float*)d_in[10];
    const float* gW1 = (const float*)d_in[11]; const float* gb1 = (const float*)d_in[12];
    const float* gW2 = (const float*)d_in[13]; const float* gb2 = (const float*)d_in[14];
    const float* fW  = (const float*)d_in[15]; const float* fb  = (const float*)d_in[16];
    const float* qW1 = (const float*)d_in[17]; const float* qb1 = (const float*)d_in[18];
    const float* qW2 = (const float*)d_in[19]; const float* qb2 = (const float*)d_in[20];
    float* out = (float*)d_out;

    int N = in_sizes[2];            // 50000
    int E = in_sizes[1] / 2;        // 800000
    int S = in_sizes[4] / FEAT;     // 256
    int L = in_sizes[3] / S;        // 128

    int nbuckets = (N + 255) / 256;     // 196 (u16 src requires N < 65535)
    int nchunks  = (E + 4095) / 4096;   // 196 (<=256 for scans)

    char* p = (char*)d_ws;
    unsigned* tmp  = (unsigned*)p;             p += (size_t)E * 4;
    u16* csr2      = (u16*)p;                  p += (size_t)nbuckets * MAXSEG * 2;
    float* hf      = (float*)p;                p += (size_t)N * 64 * 4;
    u16* hwb       = (u16*)p;                  p += (size_t)4 * (N + 1) * 16 * 2;
    u16* xp        = (u16*)p;                  p += (size_t)(N + 1) * 16 * 2;
    float* aggx    = (float*)p;                p += (size_t)N * 16 * 4;
    int* row_start = (int*)p;                  p += (size_t)N * 4;
    int* row_cntp  = (int*)p;                  p += (size_t)N * 4;
    float* dinv    = (float*)p;                p += (size_t)N * 4;
    float* gsum    = (float*)p;                p += 64 * 4;
    int* cnt2T     = (int*)p;                  p += (size_t)nbuckets * nchunks * 4;
    int* off2L     = (int*)p;                  p += (size_t)nbuckets * nchunks * 4;
    int* tot       = (int*)p;                  p += 256 * 4;
    int* base      = (int*)p;

    hipMemsetAsync(gsum, 0, 64 * 4, stream);

    const int* src = edge;
    const int* dst = edge + E;

    int gMM = (N + 63) / 64;
    int nodeBlocks = (N + 127) / 128;
    int gGB = 4 * nodeBlocks;
    int gPX = (N * 16 + 255) / 256;

    histA<<<nchunks, 1024, 0, stream>>>(dst, cnt2T, E, nbuckets, nchunks);
    off2_local<<<nbuckets, 256, 0, stream>>>(cnt2T, off2L, tot, nchunks);
    base_scan<<<1, 256, 0, stream>>>(tot, base, nbuckets);
    binpass<<<nchunks, 1024, 0, stream>>>(src, dst, base, off2L, tmp, E, nbuckets, nchunks);
    csr_build<<<nbuckets, 1024, 0, stream>>>(tmp, base, tot, csr2, row_start, row_cntp, dinv, N);
    zero_sentinel<<<1, 128, 0, stream>>>(hwb, xp, N);

    pad_x<<<gPX, 256, 0, stream>>>(x, dinv, xp, N);
    gather_x<<<nodeBlocks, 256, 0, stream>>>(row_start, row_cntp, csr2, xp, dinv, aggx, N);
    gcn_matmul1<<<gMM, 256, 0, stream>>>(aggx, W1, b1, hf, N);

    gcn_matmul64<<<gMM, 256, 0, stream>>>(hf, W2, dinv, hwb, N);
    gather_bf<<<gGB, 256, 0, stream>>>(row_start, row_cntp, csr2, hwb, dinv, b2, hf, gsum, N, 0);

    gcn_matmul64<<<gMM, 256, 0, stream>>>(hf, W3, dinv, hwb, N);
    gather_bf<<<gGB, 256, 0, stream>>>(row_start, row_cntp, csr2, hwb, dinv, b3, hf, gsum, N, 1);

    final_kernel<<<S, 256, 0, stream>>>(hf, sheet_idx, sheet_feat, gsum,
                                        gW1, gb1, gW2, gb2, fW, fb,
                                        qW1, qb1, qW2, qb2, out, N, L);
}